// Round 6
// baseline (133.625 us; speedup 1.0000x reference)
//
#include <hip/hip_runtime.h>

#define BATCH 16
#define NNODES 50000
#define NEDGES 1600000
#define BN (BATCH * NNODES)
#define CLAMP_LO -10.0f
#define CLAMP_HI 10.0f
#define EPS_V 1e-6f

// ---- binning geometry ----
#define BSZ 64                  // nodes per bin
#define NBINS 782               // ceil(50000/64)
#define CAPE 2816               // per-bin capacity: mean 2048, +17 sd
#define RPT 11                  // register-cached entries/thread: 11*256 == CAPE
#define NBLK_P 512              // prep blocks: exactly 2.0/CU (was 391 = 1.53/CU, 24% tail)
#define EPB 3200                // edges per prep block (512*3200 >= NEDGES)
#define E4PB 800                // int4-edges per block
#define NE4 (NEDGES / 4)

// ---- pass 1: hist + claim, transpose moved AFTER claim to hide atomic latency ----
__global__ __launch_bounds__(256) void prep_fused(
    const float* __restrict__ o_pre, const float* __restrict__ E,
    const int* __restrict__ src, const int* __restrict__ dst,
    const float* __restrict__ w,
    float* __restrict__ o_t, float* __restrict__ E_t,
    uint2* __restrict__ binned, int* __restrict__ gcur) {
    __shared__ int lh[NBINS];
    const int tid = threadIdx.x, bid = blockIdx.x;
    for (int i = tid; i < NBINS; i += 256) lh[i] = 0;

    // single coalesced read of this block's edge data into registers
    const int4*   dst4 = (const int4*)dst;
    const int4*   src4 = (const int4*)src;
    const float4* w4   = (const float4*)w;
    const int e4base = bid * E4PB;
    const int e4end  = (e4base + E4PB < NE4) ? (e4base + E4PB) : NE4;
    int4 d[4], s[4];
    float4 ww[4];
    bool val[4];
#pragma unroll
    for (int j = 0; j < 4; ++j) {
        int i4 = e4base + j * 256 + tid;
        val[j] = (i4 < e4end);
        if (val[j]) { d[j] = dst4[i4]; s[j] = src4[i4]; ww[j] = w4[i4]; }
    }
    __syncthreads();                 // lh zeroed

    // local histogram from registers
#pragma unroll
    for (int j = 0; j < 4; ++j) {
        if (val[j]) {
            atomicAdd(&lh[d[j].x >> 6], 1);
            atomicAdd(&lh[d[j].y >> 6], 1);
            atomicAdd(&lh[d[j].z >> 6], 1);
            atomicAdd(&lh[d[j].w >> 6], 1);
        }
    }
    __syncthreads();

    // claim a contiguous range per bin via one global atomic; lh becomes cursor
    for (int i = tid; i < NBINS; i += 256) {
        int c = lh[i];
        int base = c ? atomicAdd(&gcur[i], c) : 0;
        lh[i] = i * CAPE + base;
    }

    // fused transpose (o_pre, E) -> node-major (N,16), placed HERE so its
    // independent global traffic hides the claim atomics' round-trip latency
    {
        int task = bid * 256 + tid;      // 131072 tasks >= 100000
        int t = task >> 1;
        int h = (task & 1) * 8;
        if (t < NNODES) {
            float v[8], u[8];
#pragma unroll
            for (int j = 0; j < 8; ++j) {
                v[j] = o_pre[(h + j) * NNODES + t];   // coalesced across t
                u[j] = E[(h + j) * NNODES + t];
            }
            float4* op = (float4*)(o_t + (size_t)t * BATCH + h);
            float4* ep = (float4*)(E_t + (size_t)t * BATCH + h);
            op[0] = make_float4(v[0], v[1], v[2], v[3]);
            op[1] = make_float4(v[4], v[5], v[6], v[7]);
            ep[0] = make_float4(u[0], u[1], u[2], u[3]);
            ep[1] = make_float4(u[4], u[5], u[6], u[7]);
        }
    }
    __syncthreads();                 // claims + cursors ready

    // scatter from registers into fixed-stride bins
#pragma unroll
    for (int j = 0; j < 4; ++j) {
        if (val[j]) {
            int   dd[4] = {d[j].x, d[j].y, d[j].z, d[j].w};
            int   ss[4] = {s[j].x, s[j].y, s[j].z, s[j].w};
            float wv[4] = {ww[j].x, ww[j].y, ww[j].z, ww[j].w};
#pragma unroll
            for (int m = 0; m < 4; ++m) {
                int dn  = dd[m];
                int bin = dn >> 6;
                int pos = atomicAdd(&lh[bin], 1);   // LDS atomic
                if (pos < (bin + 1) * CAPE)
                    binned[pos] = make_uint2(
                        (unsigned)ss[m] | ((unsigned)(dn & 63) << 16),
                        __float_as_uint(wv[m]));
            }
        }
    }
}

// ---- pass 2 (R5 verbatim): register-cached sub-sort + SW-pipelined gather ----
__global__ __launch_bounds__(256, 4) void bin_gather9(
    const float* __restrict__ o_t, const float* __restrict__ E_t,
    const float* __restrict__ chem, const float* __restrict__ threshold,
    const float* __restrict__ decay, const int* __restrict__ gcur,
    const uint2* __restrict__ binned,
    float* __restrict__ out_o, float* __restrict__ out_e) {
    __shared__ int   cnt_l[BSZ];
    __shared__ int   offs[BSZ + 1];
    __shared__ uint2 eb[CAPE];      // 22.5 KB
    const int k = blockIdx.x, tid = threadIdx.x;
    const int node0 = k * BSZ;
    const int nn = (NNODES - node0 < BSZ) ? (NNODES - node0) : BSZ;
    const int s0 = k * CAPE;
    int cnt = gcur[k];              // cursor final value == bin total
    if (cnt > CAPE) cnt = CAPE;

    // A1: ONE coalesced global pass -> register cache + per-node counts
    uint2 r[RPT];
    if (tid < BSZ) cnt_l[tid] = 0;
    __syncthreads();
#pragma unroll
    for (int j = 0; j < RPT; ++j) {
        int idx = tid + j * 256;
        if (idx < cnt) {
            uint2 p = binned[s0 + idx];
            r[j] = p;
            atomicAdd(&cnt_l[(p.x >> 16) & 63], 1);
        }
    }
    __syncthreads();

    // A2: barrier-free exclusive scan of 64 counts on wave 0
    if (tid < BSZ) {
        int c = cnt_l[tid];
        int v = c;
#pragma unroll
        for (int o = 1; o < BSZ; o <<= 1) {
            int u = __shfl_up(v, o);
            if (tid >= o) v += u;
        }
        offs[tid]  = v - c;
        cnt_l[tid] = v - c;          // cursor
        if (tid == BSZ - 1) offs[BSZ] = cnt;
    }
    __syncthreads();

    // A3: scatter from registers into node-sorted LDS array
#pragma unroll
    for (int j = 0; j < RPT; ++j) {
        int idx = tid + j * 256;
        if (idx < cnt) {
            uint2 p = r[j];
            int pos = atomicAdd(&cnt_l[(p.x >> 16) & 63], 1);
            eb[pos] = p;
        }
    }
    __syncthreads();

    // B+C: one thread per (node, batch-quad); explicit 2-stage pipeline
    if (tid < nn * 4) {
        const int n  = tid >> 2;
        const int q4 = (tid & 3) * 4;
        const int gn = node0 + n;
        const int e0 = offs[n], e1 = offs[n + 1];
        const float4 en = *(const float4*)(E_t + (size_t)gn * BATCH + q4);
        const float th = threshold[gn];
        const float dc = decay[gn];
        float ch[4];
#pragma unroll
        for (int j = 0; j < 4; ++j) ch[j] = chem[(q4 + j) * NNODES + gn];

        float4 acc = make_float4(0.f, 0.f, 0.f, 0.f);
#define OJ(P) (*(const float4*)(o_t + (size_t)((P).x & 0xFFFFu) * BATCH + q4))
#define ACCP(OJV, P)                                                            \
        {                                                                       \
            float wv = __uint_as_float((P).y), nwv = -wv;                       \
            acc.x = fmaf((OJV).x, ((OJV).x >= en.x) ? wv : nwv, acc.x);         \
            acc.y = fmaf((OJV).y, ((OJV).y >= en.y) ? wv : nwv, acc.y);         \
            acc.z = fmaf((OJV).z, ((OJV).z >= en.z) ? wv : nwv, acc.z);         \
            acc.w = fmaf((OJV).w, ((OJV).w >= en.w) ? wv : nwv, acc.w);         \
        }
        int i = e0;
        uint2 p0, p1;
        float4 o0, o1;
        bool staged = false;
        if (i + 2 <= e1) {                 // prologue: stage first pair
            p0 = eb[i]; p1 = eb[i + 1];
            o0 = OJ(p0); o1 = OJ(p1);
            i += 2;
            staged = true;
        }
        for (; i + 2 <= e1; i += 2) {      // steady state: prefetch then compute
            uint2 q0 = eb[i], q1 = eb[i + 1];
            float4 n0 = OJ(q0), n1 = OJ(q1);   // next pair's loads in flight
            ACCP(o0, p0); ACCP(o1, p1);        // compute previous pair
            p0 = q0; p1 = q1; o0 = n0; o1 = n1;
        }
        if (staged) { ACCP(o0, p0); ACCP(o1, p1); }   // drain
        if (i < e1) {                       // odd tail
            uint2 pt = eb[i];
            float4 ot = OJ(pt);
            ACCP(ot, pt);
        }
#undef ACCP
#undef OJ

        float ev[4] = {en.x, en.y, en.z, en.w};
        float av[4] = {acc.x, acc.y, acc.z, acc.w};
#pragma unroll
        for (int j = 0; j < 4; ++j) {
            float e = ev[j];
            float S = e + ch[j] + av[j];
            S = fminf(fmaxf(S, CLAMP_LO), CLAMP_HI);
            float no = fmaxf(S - th, 0.0f);
            float ne;
            if (S > th) ne = no;
            else if (fabsf(S - e) <= EPS_V) ne = e - dc;
            else ne = S;
            out_o[(q4 + j) * NNODES + gn] = no;
            out_e[(q4 + j) * NNODES + gn] = ne;
        }
    }
}

// ---------- fallback: device-scope atomic path (needs no workspace) ----------
__global__ void edge_scatter_dev(const float* __restrict__ o_pre, const float* __restrict__ E,
                                 const float* __restrict__ w, const int* __restrict__ src,
                                 const int* __restrict__ dst, float* __restrict__ gj) {
    int e = blockIdx.x * blockDim.x + threadIdx.x;
    if (e >= NEDGES) return;
    int s = src[e];
    int d = dst[e];
    float wv = w[e];
#pragma unroll
    for (int b = 0; b < BATCH; ++b) {
        float oj = o_pre[b * NNODES + s];
        float en = E[b * NNODES + d];
        atomicAdd(&gj[b * NNODES + d], (oj >= en) ? oj * wv : -oj * wv);
    }
}

__global__ void finalize_dev(const float* __restrict__ chem, const float* __restrict__ E,
                             const float* __restrict__ threshold, const float* __restrict__ decay,
                             float* __restrict__ out_o, float* __restrict__ out_e_gj) {
    int i = blockIdx.x * blockDim.x + threadIdx.x;
    if (i >= BN) return;
    int n = i % NNODES;
    float e = E[i];
    float S = e + chem[i] + out_e_gj[i];
    S = fminf(fmaxf(S, CLAMP_LO), CLAMP_HI);
    float th = threshold[n];
    float no = fmaxf(S - th, 0.0f);
    float ne;
    if (S > th) ne = no;
    else if (fabsf(S - e) <= EPS_V) ne = e - decay[n];
    else ne = S;
    out_o[i] = no;
    out_e_gj[i] = ne;
}

extern "C" void kernel_launch(void* const* d_in, const int* in_sizes, int n_in,
                              void* d_out, int out_size, void* d_ws, size_t ws_size,
                              hipStream_t stream) {
    const float* chem      = (const float*)d_in[0];
    const float* E         = (const float*)d_in[1];
    const float* o_pre     = (const float*)d_in[2];
    const float* w         = (const float*)d_in[3];
    const float* threshold = (const float*)d_in[4];
    const float* decay     = (const float*)d_in[5];
    const int*   src       = (const int*)d_in[6];
    const int*   dst       = (const int*)d_in[7];

    float* out_o = (float*)d_out;
    float* out_e = (float*)d_out + BN;

    const size_t OT_OFF  = 0;                                   // 50048*16*4
    const size_t ET_OFF  = 3203072;
    const size_t BIN_OFF = 6406144;                             // NBINS*CAPE*8 = 17616896
    const size_t GC_OFF  = 24023040;
    const size_t need    = GC_OFF + (size_t)NBINS * sizeof(int);

    if (ws_size >= need) {
        char* ws = (char*)d_ws;
        float* o_t    = (float*)(ws + OT_OFF);
        float* E_t    = (float*)(ws + ET_OFF);
        uint2* binned = (uint2*)(ws + BIN_OFF);
        int*   gcur   = (int*)(ws + GC_OFF);

        hipMemsetAsync(gcur, 0, (size_t)NBINS * sizeof(int), stream);
        prep_fused<<<NBLK_P, 256, 0, stream>>>(o_pre, E, src, dst, w, o_t, E_t, binned, gcur);
        bin_gather9<<<NBINS, 256, 0, stream>>>(o_t, E_t, chem, threshold, decay,
                                               gcur, binned, out_o, out_e);
    } else {
        hipMemsetAsync(out_e, 0, (size_t)BN * sizeof(float), stream);
        edge_scatter_dev<<<(NEDGES + 255) / 256, 256, 0, stream>>>(o_pre, E, w, src, dst, out_e);
        finalize_dev<<<(BN + 255) / 256, 256, 0, stream>>>(chem, E, threshold, decay, out_o, out_e);
    }
}

// Round 7
// 122.066 us; speedup vs baseline: 1.0947x; 1.0947x over previous
//
#include <hip/hip_runtime.h>

#define BATCH 16
#define NNODES 50000
#define NEDGES 1600000
#define BN (BATCH * NNODES)
#define CLAMP_LO -10.0f
#define CLAMP_HI 10.0f
#define EPS_V 1e-6f

// ---- binning geometry (R1/R5 config) ----
#define BSZ 64                  // nodes per bin
#define NBINS 782               // ceil(50000/64)
#define CAPE 2816               // per-bin capacity: mean 2048, +17 sd
#define RPT 11                  // register-cached entries/thread: 11*256 == CAPE
#define NBLK_P 391              // prep blocks
#define EPB 4096                // edges per prep block (391*4096 >= NEDGES)

// ---- pass 1: R5 structure, 512 threads (3.05 waves/SIMD vs 1.53) ----
// Phase order law (R6): ALL global loads issue first; no VMEM between claim
// and scatter. Only change vs R5: thread count 256->512, per-thread work halved.
__global__ __launch_bounds__(512) void prep_fused(
    const float* __restrict__ o_pre, const float* __restrict__ E,
    const int* __restrict__ src, const int* __restrict__ dst,
    const float* __restrict__ w,
    float* __restrict__ o_t, float* __restrict__ E_t,
    uint2* __restrict__ binned, int* __restrict__ gcur) {
    __shared__ int lh[NBINS];
    const int tid = threadIdx.x, bid = blockIdx.x;
    for (int i = tid; i < NBINS; i += 512) lh[i] = 0;

    // single coalesced read of this block's edge data into registers (8 edges/thread)
    const int4*   dst4 = (const int4*)dst;
    const int4*   src4 = (const int4*)src;
    const float4* w4   = (const float4*)w;
    const int e4base = bid * (EPB / 4);
    int4 d[2], s[2];
    float4 ww[2];
    bool val[2];
#pragma unroll
    for (int j = 0; j < 2; ++j) {
        int i4 = e4base + j * 512 + tid;
        val[j] = (i4 < NEDGES / 4);
        if (val[j]) { d[j] = dst4[i4]; s[j] = src4[i4]; ww[j] = w4[i4]; }
    }

    // fused transpose (o_pre, E) -> node-major (N,16) — identical pattern to R5;
    // its VMEM stays in flight during the histogram phase below.
    if (tid < 128) {
        int t = bid * 128 + tid;
        if (t < NNODES) {
            float v[BATCH], u[BATCH];
#pragma unroll
            for (int b = 0; b < BATCH; ++b) {
                v[b] = o_pre[b * NNODES + t];   // coalesced across t
                u[b] = E[b * NNODES + t];
            }
            float4* op = (float4*)(o_t + (size_t)t * BATCH);
            float4* ep = (float4*)(E_t + (size_t)t * BATCH);
#pragma unroll
            for (int k = 0; k < 4; ++k) {
                op[k] = make_float4(v[4*k], v[4*k+1], v[4*k+2], v[4*k+3]);
                ep[k] = make_float4(u[4*k], u[4*k+1], u[4*k+2], u[4*k+3]);
            }
        }
    }
    __syncthreads();                 // lh zeroed

    // local histogram from registers
#pragma unroll
    for (int j = 0; j < 2; ++j) {
        if (val[j]) {
            atomicAdd(&lh[d[j].x >> 6], 1);
            atomicAdd(&lh[d[j].y >> 6], 1);
            atomicAdd(&lh[d[j].z >> 6], 1);
            atomicAdd(&lh[d[j].w >> 6], 1);
        }
    }
    __syncthreads();

    // claim a contiguous range per bin via one global atomic; lh becomes cursor
    for (int i = tid; i < NBINS; i += 512) {
        int c = lh[i];
        int base = c ? atomicAdd(&gcur[i], c) : 0;
        lh[i] = i * CAPE + base;
    }
    __syncthreads();

    // scatter from registers into fixed-stride bins
#pragma unroll
    for (int j = 0; j < 2; ++j) {
        if (val[j]) {
            int   dd[4] = {d[j].x, d[j].y, d[j].z, d[j].w};
            int   ss[4] = {s[j].x, s[j].y, s[j].z, s[j].w};
            float wv[4] = {ww[j].x, ww[j].y, ww[j].z, ww[j].w};
#pragma unroll
            for (int m = 0; m < 4; ++m) {
                int dn  = dd[m];
                int bin = dn >> 6;
                int pos = atomicAdd(&lh[bin], 1);   // LDS atomic
                if (pos < (bin + 1) * CAPE)
                    binned[pos] = make_uint2(
                        (unsigned)ss[m] | ((unsigned)(dn & 63) << 16),
                        __float_as_uint(wv[m]));
            }
        }
    }
}

// ---- pass 2 (R5 verbatim): register-cached sub-sort + SW-pipelined gather ----
__global__ __launch_bounds__(256, 4) void bin_gather9(
    const float* __restrict__ o_t, const float* __restrict__ E_t,
    const float* __restrict__ chem, const float* __restrict__ threshold,
    const float* __restrict__ decay, const int* __restrict__ gcur,
    const uint2* __restrict__ binned,
    float* __restrict__ out_o, float* __restrict__ out_e) {
    __shared__ int   cnt_l[BSZ];
    __shared__ int   offs[BSZ + 1];
    __shared__ uint2 eb[CAPE];      // 22.5 KB
    const int k = blockIdx.x, tid = threadIdx.x;
    const int node0 = k * BSZ;
    const int nn = (NNODES - node0 < BSZ) ? (NNODES - node0) : BSZ;
    const int s0 = k * CAPE;
    int cnt = gcur[k];              // cursor final value == bin total
    if (cnt > CAPE) cnt = CAPE;

    // A1: ONE coalesced global pass -> register cache + per-node counts
    uint2 r[RPT];
    if (tid < BSZ) cnt_l[tid] = 0;
    __syncthreads();
#pragma unroll
    for (int j = 0; j < RPT; ++j) {
        int idx = tid + j * 256;
        if (idx < cnt) {
            uint2 p = binned[s0 + idx];
            r[j] = p;
            atomicAdd(&cnt_l[(p.x >> 16) & 63], 1);
        }
    }
    __syncthreads();

    // A2: barrier-free exclusive scan of 64 counts on wave 0
    if (tid < BSZ) {
        int c = cnt_l[tid];
        int v = c;
#pragma unroll
        for (int o = 1; o < BSZ; o <<= 1) {
            int u = __shfl_up(v, o);
            if (tid >= o) v += u;
        }
        offs[tid]  = v - c;
        cnt_l[tid] = v - c;          // cursor
        if (tid == BSZ - 1) offs[BSZ] = cnt;
    }
    __syncthreads();

    // A3: scatter from registers into node-sorted LDS array
#pragma unroll
    for (int j = 0; j < RPT; ++j) {
        int idx = tid + j * 256;
        if (idx < cnt) {
            uint2 p = r[j];
            int pos = atomicAdd(&cnt_l[(p.x >> 16) & 63], 1);
            eb[pos] = p;
        }
    }
    __syncthreads();

    // B+C: one thread per (node, batch-quad); explicit 2-stage pipeline
    if (tid < nn * 4) {
        const int n  = tid >> 2;
        const int q4 = (tid & 3) * 4;
        const int gn = node0 + n;
        const int e0 = offs[n], e1 = offs[n + 1];
        const float4 en = *(const float4*)(E_t + (size_t)gn * BATCH + q4);
        const float th = threshold[gn];
        const float dc = decay[gn];
        float ch[4];
#pragma unroll
        for (int j = 0; j < 4; ++j) ch[j] = chem[(q4 + j) * NNODES + gn];

        float4 acc = make_float4(0.f, 0.f, 0.f, 0.f);
#define OJ(P) (*(const float4*)(o_t + (size_t)((P).x & 0xFFFFu) * BATCH + q4))
#define ACCP(OJV, P)                                                            \
        {                                                                       \
            float wv = __uint_as_float((P).y), nwv = -wv;                       \
            acc.x = fmaf((OJV).x, ((OJV).x >= en.x) ? wv : nwv, acc.x);         \
            acc.y = fmaf((OJV).y, ((OJV).y >= en.y) ? wv : nwv, acc.y);         \
            acc.z = fmaf((OJV).z, ((OJV).z >= en.z) ? wv : nwv, acc.z);         \
            acc.w = fmaf((OJV).w, ((OJV).w >= en.w) ? wv : nwv, acc.w);         \
        }
        int i = e0;
        uint2 p0, p1;
        float4 o0, o1;
        bool staged = false;
        if (i + 2 <= e1) {                 // prologue: stage first pair
            p0 = eb[i]; p1 = eb[i + 1];
            o0 = OJ(p0); o1 = OJ(p1);
            i += 2;
            staged = true;
        }
        for (; i + 2 <= e1; i += 2) {      // steady state: prefetch then compute
            uint2 q0 = eb[i], q1 = eb[i + 1];
            float4 n0 = OJ(q0), n1 = OJ(q1);   // next pair's loads in flight
            ACCP(o0, p0); ACCP(o1, p1);        // compute previous pair
            p0 = q0; p1 = q1; o0 = n0; o1 = n1;
        }
        if (staged) { ACCP(o0, p0); ACCP(o1, p1); }   // drain
        if (i < e1) {                       // odd tail
            uint2 pt = eb[i];
            float4 ot = OJ(pt);
            ACCP(ot, pt);
        }
#undef ACCP
#undef OJ

        float ev[4] = {en.x, en.y, en.z, en.w};
        float av[4] = {acc.x, acc.y, acc.z, acc.w};
#pragma unroll
        for (int j = 0; j < 4; ++j) {
            float e = ev[j];
            float S = e + ch[j] + av[j];
            S = fminf(fmaxf(S, CLAMP_LO), CLAMP_HI);
            float no = fmaxf(S - th, 0.0f);
            float ne;
            if (S > th) ne = no;
            else if (fabsf(S - e) <= EPS_V) ne = e - dc;
            else ne = S;
            out_o[(q4 + j) * NNODES + gn] = no;
            out_e[(q4 + j) * NNODES + gn] = ne;
        }
    }
}

// ---------- fallback: device-scope atomic path (needs no workspace) ----------
__global__ void edge_scatter_dev(const float* __restrict__ o_pre, const float* __restrict__ E,
                                 const float* __restrict__ w, const int* __restrict__ src,
                                 const int* __restrict__ dst, float* __restrict__ gj) {
    int e = blockIdx.x * blockDim.x + threadIdx.x;
    if (e >= NEDGES) return;
    int s = src[e];
    int d = dst[e];
    float wv = w[e];
#pragma unroll
    for (int b = 0; b < BATCH; ++b) {
        float oj = o_pre[b * NNODES + s];
        float en = E[b * NNODES + d];
        atomicAdd(&gj[b * NNODES + d], (oj >= en) ? oj * wv : -oj * wv);
    }
}

__global__ void finalize_dev(const float* __restrict__ chem, const float* __restrict__ E,
                             const float* __restrict__ threshold, const float* __restrict__ decay,
                             float* __restrict__ out_o, float* __restrict__ out_e_gj) {
    int i = blockIdx.x * blockDim.x + threadIdx.x;
    if (i >= BN) return;
    int n = i % NNODES;
    float e = E[i];
    float S = e + chem[i] + out_e_gj[i];
    S = fminf(fmaxf(S, CLAMP_LO), CLAMP_HI);
    float th = threshold[n];
    float no = fmaxf(S - th, 0.0f);
    float ne;
    if (S > th) ne = no;
    else if (fabsf(S - e) <= EPS_V) ne = e - decay[n];
    else ne = S;
    out_o[i] = no;
    out_e_gj[i] = ne;
}

extern "C" void kernel_launch(void* const* d_in, const int* in_sizes, int n_in,
                              void* d_out, int out_size, void* d_ws, size_t ws_size,
                              hipStream_t stream) {
    const float* chem      = (const float*)d_in[0];
    const float* E         = (const float*)d_in[1];
    const float* o_pre     = (const float*)d_in[2];
    const float* w         = (const float*)d_in[3];
    const float* threshold = (const float*)d_in[4];
    const float* decay     = (const float*)d_in[5];
    const int*   src       = (const int*)d_in[6];
    const int*   dst       = (const int*)d_in[7];

    float* out_o = (float*)d_out;
    float* out_e = (float*)d_out + BN;

    const size_t OT_OFF  = 0;                                   // 50048*16*4
    const size_t ET_OFF  = 3203072;
    const size_t BIN_OFF = 6406144;                             // NBINS*CAPE*8 = 17616896
    const size_t GC_OFF  = 24023040;
    const size_t need    = GC_OFF + (size_t)NBINS * sizeof(int);

    if (ws_size >= need) {
        char* ws = (char*)d_ws;
        float* o_t    = (float*)(ws + OT_OFF);
        float* E_t    = (float*)(ws + ET_OFF);
        uint2* binned = (uint2*)(ws + BIN_OFF);
        int*   gcur   = (int*)(ws + GC_OFF);

        hipMemsetAsync(gcur, 0, (size_t)NBINS * sizeof(int), stream);
        prep_fused<<<NBLK_P, 512, 0, stream>>>(o_pre, E, src, dst, w, o_t, E_t, binned, gcur);
        bin_gather9<<<NBINS, 256, 0, stream>>>(o_t, E_t, chem, threshold, decay,
                                               gcur, binned, out_o, out_e);
    } else {
        hipMemsetAsync(out_e, 0, (size_t)BN * sizeof(float), stream);
        edge_scatter_dev<<<(NEDGES + 255) / 256, 256, 0, stream>>>(o_pre, E, w, src, dst, out_e);
        finalize_dev<<<(BN + 255) / 256, 256, 0, stream>>>(chem, E, threshold, decay, out_o, out_e);
    }
}